// Round 8
// baseline (581.516 us; speedup 1.0000x reference)
//
#include <hip/hip_runtime.h>

#define NN_TOT 208896      // 32*96*68 nodes
#define E_TOT  1671168     // NN_TOT*8 edges
#define B_SZ   32
#define T_SZ   96
#define NPF    68          // nodes per frame
#define HID    128

typedef _Float16 f16x8 __attribute__((ext_vector_type(8)));
typedef _Float16 f16x2v __attribute__((ext_vector_type(2)));
typedef float f32x4 __attribute__((ext_vector_type(4)));

// ---------------- degree count (int4, 4 atomics/thread) ----------------
__global__ __launch_bounds__(256) void k_deg(const int4* __restrict__ dst4, int* __restrict__ cnt) {
    int e = blockIdx.x * 256 + threadIdx.x;
    int4 d = dst4[e];
    atomicAdd(&cnt[d.x], 1);
    atomicAdd(&cnt[d.y], 1);
    atomicAdd(&cnt[d.z], 1);
    atomicAdd(&cnt[d.w], 1);
}

// ---------------- scan part 1 (+ fused deg->norm) ----------------
__global__ __launch_bounds__(256) void k_scan1(const int* __restrict__ cnt, int* __restrict__ row_off,
                                               int* __restrict__ bsums, float* __restrict__ d_isqrt,
                                               float* __restrict__ self_norm) {
    __shared__ int ts[256];
    int tid = threadIdx.x;
    int base = blockIdx.x * 1024 + tid * 4;
    int v0 = cnt[base], v1 = cnt[base + 1], v2 = cnt[base + 2], v3 = cnt[base + 3];
#pragma unroll
    for (int u = 0; u < 4; ++u) {
        int vv = (u == 0) ? v0 : (u == 1) ? v1 : (u == 2) ? v2 : v3;
        float deg = (float)(1 + vv);
        float is = 1.0f / sqrtf(deg);
        d_isqrt[base + u] = is;
        self_norm[base + u] = is * is;
    }
    int s = v0 + v1 + v2 + v3;
    ts[tid] = s;
    __syncthreads();
    int inc = s;
    for (int off = 1; off < 256; off <<= 1) {
        int add = (tid >= off) ? ts[tid - off] : 0;
        __syncthreads();
        inc += add;
        ts[tid] = inc;
        __syncthreads();
    }
    int excl = inc - s;
    row_off[base] = excl;
    row_off[base + 1] = excl + v0;
    row_off[base + 2] = excl + v0 + v1;
    row_off[base + 3] = excl + v0 + v1 + v2;
    if (tid == 255) bsums[blockIdx.x] = inc;
}

__global__ __launch_bounds__(256) void k_scan2(int* __restrict__ bsums, int nb) {
    __shared__ int ts[256];
    int tid = threadIdx.x;
    int v = (tid < nb) ? bsums[tid] : 0;
    ts[tid] = v;
    __syncthreads();
    int inc = v;
    for (int off = 1; off < 256; off <<= 1) {
        int add = (tid >= off) ? ts[tid - off] : 0;
        __syncthreads();
        inc += add;
        ts[tid] = inc;
        __syncthreads();
    }
    if (tid < nb) bsums[tid] = inc - v;
}

__global__ __launch_bounds__(256) void k_scan3(int* __restrict__ row_off, const int* __restrict__ bsums) {
    int i = blockIdx.x * 256 + threadIdx.x;
    row_off[i] += bsums[i >> 10];
    if (i == 0) row_off[NN_TOT] = E_TOT;
}

// ---------------- CSR scatter: packed (src, norm) int2 ----------------
__global__ __launch_bounds__(256) void k_scatter(const int* __restrict__ src, const int* __restrict__ dst,
                                                 const float* __restrict__ d_isqrt, const int* __restrict__ row_off,
                                                 int* __restrict__ cursor, int2* __restrict__ er) {
    int e = blockIdx.x * 256 + threadIdx.x;
    int s = src[e], d = dst[e];
    float en = d_isqrt[s] * d_isqrt[d];
    int p = atomicAdd(&cursor[d], 1);
    int idx = row_off[d] + p;
    er[idx] = make_int2(s, __float_as_int(en));
}

// ---------------- GCN layer 0: 64 nodes/block, 4 edge-slots/node, then block matvec ----------------
__global__ __launch_bounds__(256) void k_gcn0(const float* __restrict__ x, const int* __restrict__ row_off,
                                              const int2* __restrict__ er, const float* __restrict__ self_norm,
                                              const float* __restrict__ W0, const float* __restrict__ b0,
                                              _Float16* __restrict__ h0) {
    __shared__ float zs[64][4];
    const int tid = threadIdx.x;
    const int blk = blockIdx.x;
    {
        const int li = tid >> 2;         // local node 0..63
        const int slot = tid & 3;        // edge slot
        const int n = blk * 64 + li;
        const int beg = row_off[n], end = row_off[n + 1];
        float p0 = 0.f, p1 = 0.f, p2 = 0.f;
        for (int ei = beg + slot; ei < end; ei += 4) {
            int2 e = er[ei];
            float en = __int_as_float(e.y);
            const float* xs = x + 3 * (size_t)e.x;
            p0 = fmaf(xs[0], en, p0);
            p1 = fmaf(xs[1], en, p1);
            p2 = fmaf(xs[2], en, p2);
        }
        p0 += __shfl_xor(p0, 1); p1 += __shfl_xor(p1, 1); p2 += __shfl_xor(p2, 1);
        p0 += __shfl_xor(p0, 2); p1 += __shfl_xor(p1, 2); p2 += __shfl_xor(p2, 2);
        if (slot == 0) {
            const float sn = self_norm[n];
            const float* xn = x + 3 * (size_t)n;
            zs[li][0] = fmaf(xn[0], sn, p0);
            zs[li][1] = fmaf(xn[1], sn, p1);
            zs[li][2] = fmaf(xn[2], sn, p2);
        }
    }
    __syncthreads();
    // matvec: thread = col-pair jj, 16 nodes per wave-group
    const int jj = tid & 63;                  // col pair 0..63
    const int g = tid >> 6;                   // node group 0..3
    const int j = jj * 2;
    const float w00 = W0[j], w01 = W0[j + 1];
    const float w10 = W0[128 + j], w11 = W0[128 + j + 1];
    const float w20 = W0[256 + j], w21 = W0[256 + j + 1];
    const float bb0 = b0[j], bb1 = b0[j + 1];
#pragma unroll 4
    for (int i = 0; i < 16; ++i) {
        const int li = g * 16 + i;
        const float z0 = zs[li][0], z1 = zs[li][1], z2 = zs[li][2];
        float o0 = bb0 + z0 * w00 + z1 * w10 + z2 * w20;
        float o1 = bb1 + z0 * w01 + z1 * w11 + z2 * w21;
        f16x2v o;
        o[0] = (_Float16)fmaxf(o0, 0.f);
        o[1] = (_Float16)fmaxf(o1, 0.f);
        *(f16x2v*)(h0 + (size_t)(blk * 64 + li) * HID + j) = o;
    }
}

// ---------------- fused: aggregation (lane-per-node, wave-per-feature-slice) + GEMM1 MFMA -> h1 ----
__global__ __launch_bounds__(256) void k_agg_mm(const _Float16* __restrict__ h0, const int* __restrict__ row_off,
                                                const int2* __restrict__ er, const float* __restrict__ self_norm,
                                                const _Float16* __restrict__ W1p, const float* __restrict__ b1,
                                                _Float16* __restrict__ h1) {
    __shared__ __align__(16) _Float16 As[64 * 136];  // rows padded to 136 f16 (272 B)
    const int tid = threadIdx.x;
    const int w = tid >> 6, lane = tid & 63;
    const int blk = blockIdx.x;

    // phase 1: per-lane gather-accumulate over own node's edges (cols w*32 + 0..31)
    {
        const int node = blk * 64 + lane;
        const int beg = row_off[node], end = row_off[node + 1];
        const _Float16* __restrict__ hcol = h0 + w * 32;
        f32x4 acc[8];
#pragma unroll
        for (int k = 0; k < 8; ++k) acc[k] = (f32x4){0.f, 0.f, 0.f, 0.f};
        {
            const float sn = self_norm[node];
            const f16x8* rp = (const f16x8*)(hcol + (size_t)node * HID);
#pragma unroll
            for (int v4 = 0; v4 < 4; ++v4) {
                f16x8 v = rp[v4];
#pragma unroll
                for (int k = 0; k < 8; ++k) acc[v4 * 2 + (k >> 2)][k & 3] = fmaf((float)v[k], sn, acc[v4 * 2 + (k >> 2)][k & 3]);
            }
        }
        for (int ei = beg; ei < end; ++ei) {
            int2 e = er[ei];
            float en = __int_as_float(e.y);
            const f16x8* rp = (const f16x8*)(hcol + (size_t)e.x * HID);
            f16x8 v0 = rp[0], v1 = rp[1], v2 = rp[2], v3 = rp[3];
#pragma unroll
            for (int k = 0; k < 8; ++k) acc[0 + (k >> 2)][k & 3] = fmaf((float)v0[k], en, acc[0 + (k >> 2)][k & 3]);
#pragma unroll
            for (int k = 0; k < 8; ++k) acc[2 + (k >> 2)][k & 3] = fmaf((float)v1[k], en, acc[2 + (k >> 2)][k & 3]);
#pragma unroll
            for (int k = 0; k < 8; ++k) acc[4 + (k >> 2)][k & 3] = fmaf((float)v2[k], en, acc[4 + (k >> 2)][k & 3]);
#pragma unroll
            for (int k = 0; k < 8; ++k) acc[6 + (k >> 2)][k & 3] = fmaf((float)v3[k], en, acc[6 + (k >> 2)][k & 3]);
        }
        _Float16* dst = &As[lane * 136 + w * 32];
#pragma unroll
        for (int v4 = 0; v4 < 4; ++v4) {
            f16x8 o;
#pragma unroll
            for (int k = 0; k < 8; ++k) o[k] = (_Float16)acc[v4 * 2 + (k >> 2)][k & 3];
            *(f16x8*)(dst + v4 * 8) = o;
        }
    }
    __syncthreads();

    // phase 2: MFMA 16x128x128; wave w owns m-tile rows w*16..w*16+15
    const int q = lane >> 4, c = lane & 15;
    f16x8 afr[4];
#pragma unroll
    for (int kk = 0; kk < 4; ++kk) afr[kk] = *(const f16x8*)(&As[(w * 16 + c) * 136 + kk * 32 + q * 8]);
    const f16x8* __restrict__ Bv = (const f16x8*)W1p;
    _Float16* Cst = &As[w * 2176];
#pragma unroll
    for (int j = 0; j < 8; ++j) {
        f32x4 cc = {0.f, 0.f, 0.f, 0.f};
#pragma unroll
        for (int kk = 0; kk < 4; ++kk)
            cc = __builtin_amdgcn_mfma_f32_16x16x32_f16(afr[kk], Bv[(j * 4 + kk) * 64 + lane], cc, 0, 0, 0);
        const float bi = b1[j * 16 + c];
#pragma unroll
        for (int r = 0; r < 4; ++r) Cst[(q * 4 + r) * 128 + j * 16 + c] = (_Float16)fmaxf(cc[r] + bi, 0.f);
    }
#pragma unroll
    for (int it = 0; it < 4; ++it) {
        int idx = it * 64 + lane;
        *(f16x8*)(h1 + (size_t)(blk * 64 + w * 16) * 128 + idx * 8) = *(const f16x8*)(&As[w * 2176 + idx * 8]);
    }
}

// ---------------- weight prep: WihT (f32) + MFMA fragment packs (f16) incl. Whh for GRU ----------
__global__ __launch_bounds__(256) void k_prep(const float* __restrict__ Wih, const float* __restrict__ Whh,
                                              const float* __restrict__ W1, const float* __restrict__ Wm,
                                              float* __restrict__ WihT, _Float16* __restrict__ W1p,
                                              _Float16* __restrict__ Wmp, _Float16* __restrict__ Whhp) {
    int i = blockIdx.x * 256 + threadIdx.x;  // 0..49151
    {
        int o = i >> 7, k = i & 127;
        WihT[k * 384 + o] = Wih[i];
    }
    {
        // Whh frag pack over full range: i = ((f)*64 + lane)*8 + e, f = (w*3+g)*4+kk
        int e = i & 7;
        int lane = (i >> 3) & 63;
        int f = i >> 9;  // 0..95
        int kk = f & 3, g = (f >> 2) % 3, wv = f / 12;
        int q = lane >> 4, c = lane & 15;
        Whhp[i] = (_Float16)Whh[(size_t)(g * 128 + 16 * wv + c) * 128 + kk * 32 + q * 8 + e];
    }
    if (i < 16384) {
        int f = i >> 9;          // frag id 0..31
        int j = f >> 2, kk = f & 3;
        int lane = (i >> 3) & 63;
        int e = i & 7;
        int q = lane >> 4, p = lane & 15;
        int k = kk * 32 + q * 8 + e, n = j * 16 + p;
        W1p[i] = (_Float16)W1[k * 128 + n];
        Wmp[i] = (_Float16)Wm[k * 128 + n];
    }
}

// ---------------- fused: GEMM2 (f16 MFMA) + relu + frame mean + gi precompute (time-major out) ----
__global__ __launch_bounds__(256) void k_mm_pool(const _Float16* __restrict__ h1, const _Float16* __restrict__ Wmp,
                                                 const float* __restrict__ bm, const float* __restrict__ WihT,
                                                 const float* __restrict__ bih, float* __restrict__ GIt) {
    __shared__ __align__(16) _Float16 As[80 * 136];
    __shared__ float colpart[4 * 128];
    __shared__ float fr[128];
    const int tid = threadIdx.x;
    const int w = tid >> 6, lane = tid & 63;
    const int q = lane >> 4, c = lane & 15;
    const int bt = blockIdx.x;
    const int bb = bt / T_SZ, tt = bt % T_SZ;

    const f16x8* __restrict__ srcv = (const f16x8*)(h1 + (size_t)bt * NPF * HID);
    for (int idx = tid; idx < 80 * 17; idx += 256) {
        int row = idx / 17, ch = idx % 17;
        f16x8 v;
        if (row < NPF && ch < 16) {
            v = srcv[row * 16 + ch];
        } else {
#pragma unroll
            for (int k = 0; k < 8; ++k) v[k] = (_Float16)0.f;
        }
        *(f16x8*)(&As[row * 136 + ch * 8]) = v;
    }
    __syncthreads();

    const f16x8* __restrict__ Bv = (const f16x8*)Wmp;
    const int npass = (w == 0) ? 2 : 1;
    for (int pass = 0; pass < npass; ++pass) {
        const int mt = pass ? 4 : w;
        f16x8 afr[4];
#pragma unroll
        for (int kk = 0; kk < 4; ++kk) afr[kk] = *(const f16x8*)(&As[(mt * 16 + c) * 136 + kk * 32 + q * 8]);
#pragma unroll
        for (int j = 0; j < 8; ++j) {
            f32x4 cc = {0.f, 0.f, 0.f, 0.f};
#pragma unroll
            for (int kk = 0; kk < 4; ++kk)
                cc = __builtin_amdgcn_mfma_f32_16x16x32_f16(afr[kk], Bv[(j * 4 + kk) * 64 + lane], cc, 0, 0, 0);
            const float bi = bm[j * 16 + c];
            float s = 0.f;
#pragma unroll
            for (int r = 0; r < 4; ++r) {
                int m = mt * 16 + q * 4 + r;
                float v = fmaxf(cc[r] + bi, 0.f);
                s += (m < NPF) ? v : 0.f;
            }
            s += __shfl_xor(s, 16);
            s += __shfl_xor(s, 32);
            if (lane < 16) {
                float* dst = &colpart[w * 128 + j * 16 + c];
                *dst = (pass == 0) ? s : (*dst + s);
            }
        }
    }
    __syncthreads();
    if (tid < 128)
        fr[tid] = (colpart[tid] + colpart[128 + tid] + colpart[256 + tid] + colpart[384 + tid]) * (1.0f / NPF);
    __syncthreads();
    if (tid < 128) {
#pragma unroll
        for (int p = 0; p < 3; ++p) {
            int o = tid + p * 128;
            float a = bih[o];
#pragma unroll 8
            for (int k = 0; k < 128; ++k) a = fmaf(fr[k], WihT[k * 384 + o], a);
            GIt[((size_t)tt * B_SZ + bb) * 384 + o] = a;  // time-major for the GRU
        }
    }
}

// ---------------- GRU recurrence: MFMA-batched (16 batches = M-tile), 2 blocks x 8 waves ----------
// Wave w owns n-tiles {w, 8+w, 16+w} = gates r/z/n of outputs 16w..16w+15 -> gate math is lane-local.
// waves_per_eu(1,2): per-wave budget >=256 arch VGPRs -> weight frags stay in arch regs (r7: allocator
// chose 60 VGPR for 8-wave occupancy it can't use and burned ~400 VALU inst/step on AGPR traffic).
__global__ __launch_bounds__(512) __attribute__((amdgpu_waves_per_eu(1, 2)))
void k_gru(const float* __restrict__ GIt, const _Float16* __restrict__ Whhp,
           const float* __restrict__ bhh, float* __restrict__ hT) {
    __shared__ __align__(16) _Float16 hbuf[2][16 * 144];  // double buffer: one barrier/step
    const int tid = threadIdx.x;
    const int w = tid >> 6, lane = tid & 63;
    const int q = lane >> 4, c = lane & 15;
    const int B = blockIdx.x;  // batches 16B..16B+15

    // B-frags: pre-packed f16, 12 coalesced 16B loads (48 VGPRs)
    f16x8 bfr[3][4];
#pragma unroll
    for (int g = 0; g < 3; ++g)
#pragma unroll
        for (int kk = 0; kk < 4; ++kk)
            bfr[g][kk] = *(const f16x8*)(Whhp + (size_t)(((w * 3 + g) * 4 + kk) * 64 + lane) * 8);
    const float bh0 = bhh[16 * w + c], bh1 = bhh[128 + 16 * w + c], bh2 = bhh[256 + 16 * w + c];
    for (int i = tid; i < 16 * 144 / 2; i += 512) ((unsigned int*)hbuf[0])[i] = 0u;
    float h[4] = {0.f, 0.f, 0.f, 0.f};
    float gc[3][4];
#pragma unroll
    for (int r = 0; r < 4; ++r) {
        size_t row = (size_t)(B * 16 + q * 4 + r) * 384 + 16 * w + c;  // t = 0
#pragma unroll
        for (int g = 0; g < 3; ++g) gc[g][r] = GIt[row + g * 128];
    }
    __syncthreads();

    for (int t = 0; t < T_SZ; ++t) {
        const _Float16* rb = hbuf[t & 1];
        _Float16* wb = hbuf[(t & 1) ^ 1];
        f16x8 afr[4];
#pragma unroll
        for (int kk = 0; kk < 4; ++kk) afr[kk] = *(const f16x8*)(&rb[c * 144 + kk * 32 + q * 8]);
        // prefetch next step's gi (L2-resident, hidden behind MFMA)
        float gn[3][4];
        const int tn = (t + 1 < T_SZ) ? t + 1 : T_SZ - 1;
#pragma unroll
        for (int r = 0; r < 4; ++r) {
            size_t row = ((size_t)tn * B_SZ + B * 16 + q * 4 + r) * 384 + 16 * w + c;
#pragma unroll
            for (int g = 0; g < 3; ++g) gn[g][r] = GIt[row + g * 128];
        }
        f32x4 cc[3];
#pragma unroll
        for (int g = 0; g < 3; ++g) {
            f32x4 a = {0.f, 0.f, 0.f, 0.f};
#pragma unroll
            for (int kk = 0; kk < 4; ++kk) a = __builtin_amdgcn_mfma_f32_16x16x32_f16(afr[kk], bfr[g][kk], a, 0, 0, 0);
            cc[g] = a;
        }
#pragma unroll
        for (int r = 0; r < 4; ++r) {
            float hr = cc[0][r] + bh0, hz = cc[1][r] + bh1, hn = cc[2][r] + bh2;
            float rg = 1.f / (1.f + __expf(-(gc[0][r] + hr)));
            float zg = 1.f / (1.f + __expf(-(gc[1][r] + hz)));
            float arg = gc[2][r] + rg * hn;
            float nn = 1.f - 2.f / (__expf(2.f * arg) + 1.f);
            h[r] = (1.f - zg) * nn + zg * h[r];
            wb[(q * 4 + r) * 144 + 16 * w + c] = (_Float16)h[r];
        }
#pragma unroll
        for (int r = 0; r < 4; ++r) {
            gc[0][r] = gn[0][r]; gc[1][r] = gn[1][r]; gc[2][r] = gn[2][r];
        }
        __syncthreads();  // new h visible for next step's frag reads
    }
#pragma unroll
    for (int r = 0; r < 4; ++r) hT[(size_t)(B * 16 + q * 4 + r) * 128 + 16 * w + c] = h[r];
}

// ---------------- classifier head (384 threads: phase 2 needs 320) ----------------
__global__ __launch_bounds__(384) void k_cls(const float* __restrict__ hT, const float* __restrict__ Wc1,
                                             const float* __restrict__ bc1, const float* __restrict__ Wc2,
                                             const float* __restrict__ bc2, float* __restrict__ out) {
    __shared__ float hid[32 * 64];
    int tid = threadIdx.x;
    for (int idx = tid; idx < 2048; idx += 384) {
        int b = idx >> 6, j = idx & 63;
        float a = bc1[j];
#pragma unroll 8
        for (int k = 0; k < 128; ++k) a = fmaf(hT[b * 128 + k], Wc1[k * 64 + j], a);
        hid[idx] = fmaxf(a, 0.f);
    }
    __syncthreads();
    if (tid < 320) {
        int b = tid / 10, c = tid % 10;
        float a = bc2[c];
#pragma unroll 8
        for (int k = 0; k < 64; ++k) a = fmaf(hid[b * 64 + k], Wc2[k * 10 + c], a);
        out[tid] = a;
    }
}

extern "C" void kernel_launch(void* const* d_in, const int* in_sizes, int n_in, void* d_out, int out_size, void* d_ws,
                              size_t ws_size, hipStream_t stream) {
    const float* x = (const float*)d_in[0];
    const int* ei = (const int*)d_in[1];
    const int* e_src = ei;
    const int* e_dst = ei + E_TOT;
    const float* W0 = (const float*)d_in[2];
    const float* b0 = (const float*)d_in[3];
    const float* W1 = (const float*)d_in[4];
    const float* b1 = (const float*)d_in[5];
    const float* Wm = (const float*)d_in[6];
    const float* bm = (const float*)d_in[7];
    const float* Wih = (const float*)d_in[8];
    const float* Whh = (const float*)d_in[9];
    const float* bih = (const float*)d_in[10];
    const float* bhh = (const float*)d_in[11];
    const float* Wc1 = (const float*)d_in[12];
    const float* bc1 = (const float*)d_in[13];
    const float* Wc2 = (const float*)d_in[14];
    const float* bc2 = (const float*)d_in[15];
    float* out = (float*)d_out;

    char* base = (char*)d_ws;
    size_t off = 0;
    auto alloc = [&](size_t bytes) {
        size_t o = off;
        off = (off + bytes + 255) & ~(size_t)255;
        return o;
    };
    size_t o_cnt = alloc((size_t)NN_TOT * 4);
    size_t o_cursor = alloc((size_t)NN_TOT * 4);  // contiguous with cnt for one memset
    size_t o_rowoff = alloc((size_t)(NN_TOT + 1) * 4);
    size_t o_bsums = alloc(256 * 4);
    size_t o_disqrt = alloc((size_t)NN_TOT * 4);
    size_t o_snorm = alloc((size_t)NN_TOT * 4);
    size_t o_er = alloc((size_t)E_TOT * 8);
    size_t o_gi = alloc((size_t)B_SZ * T_SZ * 384 * 4);
    size_t o_wiht = alloc((size_t)128 * 384 * 4);
    size_t o_w1p = alloc((size_t)128 * 128 * 2);
    size_t o_wmp = alloc((size_t)128 * 128 * 2);
    size_t o_whhp = alloc((size_t)128 * 384 * 2);
    size_t o_ht = alloc((size_t)B_SZ * 128 * 4);
    size_t o_h0 = alloc((size_t)NN_TOT * HID * 2);
    size_t o_h1 = alloc((size_t)NN_TOT * HID * 2);
    if (off > ws_size) return;  // workspace too small -> visible validation failure

    int* cnt = (int*)(base + o_cnt);
    int* cursor = (int*)(base + o_cursor);
    int* row_off = (int*)(base + o_rowoff);
    int* bsums = (int*)(base + o_bsums);
    float* d_isqrt = (float*)(base + o_disqrt);
    float* self_norm = (float*)(base + o_snorm);
    int2* er = (int2*)(base + o_er);
    float* GIt = (float*)(base + o_gi);
    float* WihT = (float*)(base + o_wiht);
    _Float16* W1p = (_Float16*)(base + o_w1p);
    _Float16* Wmp = (_Float16*)(base + o_wmp);
    _Float16* Whhp = (_Float16*)(base + o_whhp);
    float* hT = (float*)(base + o_ht);
    _Float16* h0 = (_Float16*)(base + o_h0);
    _Float16* h1 = (_Float16*)(base + o_h1);

    hipMemsetAsync(base + o_cnt, 0, (size_t)2 * NN_TOT * 4, stream);  // cnt + cursor

    k_deg<<<E_TOT / 1024, 256, 0, stream>>>((const int4*)e_dst, cnt);
    k_scan1<<<NN_TOT / 1024, 256, 0, stream>>>(cnt, row_off, bsums, d_isqrt, self_norm);
    k_scan2<<<1, 256, 0, stream>>>(bsums, NN_TOT / 1024);
    k_scan3<<<NN_TOT / 256, 256, 0, stream>>>(row_off, bsums);
    k_scatter<<<E_TOT / 256, 256, 0, stream>>>(e_src, e_dst, d_isqrt, row_off, cursor, er);
    k_prep<<<(384 * 128) / 256, 256, 0, stream>>>(Wih, Whh, W1, Wm, WihT, W1p, Wmp, Whhp);
    k_gcn0<<<NN_TOT / 64, 256, 0, stream>>>(x, row_off, er, self_norm, W0, b0, h0);
    k_agg_mm<<<NN_TOT / 64, 256, 0, stream>>>(h0, row_off, er, self_norm, W1p, b1, h1);
    k_mm_pool<<<B_SZ * T_SZ, 256, 0, stream>>>(h1, Wmp, bm, WihT, bih, GIt);
    k_gru<<<2, 512, 0, stream>>>(GIt, Whhp, bhh, hT);
    k_cls<<<1, 384, 0, stream>>>(hT, Wc1, bc1, Wc2, bc2, out);
}

// Round 9
// 569.370 us; speedup vs baseline: 1.0213x; 1.0213x over previous
//
#include <hip/hip_runtime.h>

#define NN_TOT 208896      // 32*96*68 nodes
#define E_TOT  1671168     // NN_TOT*8 edges
#define B_SZ   32
#define T_SZ   96
#define NPF    68          // nodes per frame
#define HID    128

typedef _Float16 f16x8 __attribute__((ext_vector_type(8)));
typedef _Float16 f16x2v __attribute__((ext_vector_type(2)));
typedef float f32x4 __attribute__((ext_vector_type(4)));

// ---------------- degree count (int4, 4 atomics/thread) ----------------
__global__ __launch_bounds__(256) void k_deg(const int4* __restrict__ dst4, int* __restrict__ cnt) {
    int e = blockIdx.x * 256 + threadIdx.x;
    int4 d = dst4[e];
    atomicAdd(&cnt[d.x], 1);
    atomicAdd(&cnt[d.y], 1);
    atomicAdd(&cnt[d.z], 1);
    atomicAdd(&cnt[d.w], 1);
}

// ---------------- scan part 1 (+ fused deg->norm) ----------------
__global__ __launch_bounds__(256) void k_scan1(const int* __restrict__ cnt, int* __restrict__ row_off,
                                               int* __restrict__ bsums, float* __restrict__ d_isqrt,
                                               float* __restrict__ self_norm) {
    __shared__ int ts[256];
    int tid = threadIdx.x;
    int base = blockIdx.x * 1024 + tid * 4;
    int v0 = cnt[base], v1 = cnt[base + 1], v2 = cnt[base + 2], v3 = cnt[base + 3];
#pragma unroll
    for (int u = 0; u < 4; ++u) {
        int vv = (u == 0) ? v0 : (u == 1) ? v1 : (u == 2) ? v2 : v3;
        float deg = (float)(1 + vv);
        float is = 1.0f / sqrtf(deg);
        d_isqrt[base + u] = is;
        self_norm[base + u] = is * is;
    }
    int s = v0 + v1 + v2 + v3;
    ts[tid] = s;
    __syncthreads();
    int inc = s;
    for (int off = 1; off < 256; off <<= 1) {
        int add = (tid >= off) ? ts[tid - off] : 0;
        __syncthreads();
        inc += add;
        ts[tid] = inc;
        __syncthreads();
    }
    int excl = inc - s;
    row_off[base] = excl;
    row_off[base + 1] = excl + v0;
    row_off[base + 2] = excl + v0 + v1;
    row_off[base + 3] = excl + v0 + v1 + v2;
    if (tid == 255) bsums[blockIdx.x] = inc;
}

__global__ __launch_bounds__(256) void k_scan2(int* __restrict__ bsums, int nb) {
    __shared__ int ts[256];
    int tid = threadIdx.x;
    int v = (tid < nb) ? bsums[tid] : 0;
    ts[tid] = v;
    __syncthreads();
    int inc = v;
    for (int off = 1; off < 256; off <<= 1) {
        int add = (tid >= off) ? ts[tid - off] : 0;
        __syncthreads();
        inc += add;
        ts[tid] = inc;
        __syncthreads();
    }
    if (tid < nb) bsums[tid] = inc - v;
}

__global__ __launch_bounds__(256) void k_scan3(int* __restrict__ row_off, const int* __restrict__ bsums) {
    int i = blockIdx.x * 256 + threadIdx.x;
    row_off[i] += bsums[i >> 10];
    if (i == 0) row_off[NN_TOT] = E_TOT;
}

// ---------------- CSR scatter: packed (src, norm) int2 ----------------
__global__ __launch_bounds__(256) void k_scatter(const int* __restrict__ src, const int* __restrict__ dst,
                                                 const float* __restrict__ d_isqrt, const int* __restrict__ row_off,
                                                 int* __restrict__ cursor, int2* __restrict__ er) {
    int e = blockIdx.x * 256 + threadIdx.x;
    int s = src[e], d = dst[e];
    float en = d_isqrt[s] * d_isqrt[d];
    int p = atomicAdd(&cursor[d], 1);
    int idx = row_off[d] + p;
    er[idx] = make_int2(s, __float_as_int(en));
}

// ---------------- GCN layer 0: 64 nodes/block, 4 edge-slots/node, then block matvec ----------------
__global__ __launch_bounds__(256) void k_gcn0(const float* __restrict__ x, const int* __restrict__ row_off,
                                              const int2* __restrict__ er, const float* __restrict__ self_norm,
                                              const float* __restrict__ W0, const float* __restrict__ b0,
                                              _Float16* __restrict__ h0) {
    __shared__ float zs[64][4];
    const int tid = threadIdx.x;
    const int blk = blockIdx.x;
    {
        const int li = tid >> 2;         // local node 0..63
        const int slot = tid & 3;        // edge slot
        const int n = blk * 64 + li;
        const int beg = row_off[n], end = row_off[n + 1];
        float p0 = 0.f, p1 = 0.f, p2 = 0.f;
        for (int ei = beg + slot; ei < end; ei += 4) {
            int2 e = er[ei];
            float en = __int_as_float(e.y);
            const float* xs = x + 3 * (size_t)e.x;
            p0 = fmaf(xs[0], en, p0);
            p1 = fmaf(xs[1], en, p1);
            p2 = fmaf(xs[2], en, p2);
        }
        p0 += __shfl_xor(p0, 1); p1 += __shfl_xor(p1, 1); p2 += __shfl_xor(p2, 1);
        p0 += __shfl_xor(p0, 2); p1 += __shfl_xor(p1, 2); p2 += __shfl_xor(p2, 2);
        if (slot == 0) {
            const float sn = self_norm[n];
            const float* xn = x + 3 * (size_t)n;
            zs[li][0] = fmaf(xn[0], sn, p0);
            zs[li][1] = fmaf(xn[1], sn, p1);
            zs[li][2] = fmaf(xn[2], sn, p2);
        }
    }
    __syncthreads();
    // matvec: thread = col-pair jj, 16 nodes per wave-group
    const int jj = tid & 63;                  // col pair 0..63
    const int g = tid >> 6;                   // node group 0..3
    const int j = jj * 2;
    const float w00 = W0[j], w01 = W0[j + 1];
    const float w10 = W0[128 + j], w11 = W0[128 + j + 1];
    const float w20 = W0[256 + j], w21 = W0[256 + j + 1];
    const float bb0 = b0[j], bb1 = b0[j + 1];
#pragma unroll 4
    for (int i = 0; i < 16; ++i) {
        const int li = g * 16 + i;
        const float z0 = zs[li][0], z1 = zs[li][1], z2 = zs[li][2];
        float o0 = bb0 + z0 * w00 + z1 * w10 + z2 * w20;
        float o1 = bb1 + z0 * w01 + z1 * w11 + z2 * w21;
        f16x2v o;
        o[0] = (_Float16)fmaxf(o0, 0.f);
        o[1] = (_Float16)fmaxf(o1, 0.f);
        *(f16x2v*)(h0 + (size_t)(blk * 64 + li) * HID + j) = o;
    }
}

// ---------------- fused: aggregation (lane-per-node, wave-per-feature-slice) + GEMM1 MFMA -> h1 ----
__global__ __launch_bounds__(256) void k_agg_mm(const _Float16* __restrict__ h0, const int* __restrict__ row_off,
                                                const int2* __restrict__ er, const float* __restrict__ self_norm,
                                                const _Float16* __restrict__ W1p, const float* __restrict__ b1,
                                                _Float16* __restrict__ h1) {
    __shared__ __align__(16) _Float16 As[64 * 136];  // rows padded to 136 f16 (272 B)
    const int tid = threadIdx.x;
    const int w = tid >> 6, lane = tid & 63;
    const int blk = blockIdx.x;

    // phase 1: per-lane gather-accumulate over own node's edges (cols w*32 + 0..31), 2-edge unroll
    {
        const int node = blk * 64 + lane;
        const int beg = row_off[node], end = row_off[node + 1];
        const _Float16* __restrict__ hcol = h0 + w * 32;
        f32x4 acc[8];
#pragma unroll
        for (int k = 0; k < 8; ++k) acc[k] = (f32x4){0.f, 0.f, 0.f, 0.f};
        {
            const float sn = self_norm[node];
            const f16x8* rp = (const f16x8*)(hcol + (size_t)node * HID);
#pragma unroll
            for (int v4 = 0; v4 < 4; ++v4) {
                f16x8 v = rp[v4];
#pragma unroll
                for (int k = 0; k < 8; ++k) acc[v4 * 2 + (k >> 2)][k & 3] = fmaf((float)v[k], sn, acc[v4 * 2 + (k >> 2)][k & 3]);
            }
        }
        int ei = beg;
        for (; ei + 2 <= end; ei += 2) {
            int2 ea = er[ei], eb = er[ei + 1];
            float ena = __int_as_float(ea.y), enb = __int_as_float(eb.y);
            const f16x8* ra = (const f16x8*)(hcol + (size_t)ea.x * HID);
            const f16x8* rbp = (const f16x8*)(hcol + (size_t)eb.x * HID);
            f16x8 a0 = ra[0], a1 = ra[1], a2 = ra[2], a3 = ra[3];
            f16x8 b0_ = rbp[0], b1_ = rbp[1], b2_ = rbp[2], b3_ = rbp[3];
#pragma unroll
            for (int k = 0; k < 8; ++k) acc[0 + (k >> 2)][k & 3] = fmaf((float)a0[k], ena, acc[0 + (k >> 2)][k & 3]);
#pragma unroll
            for (int k = 0; k < 8; ++k) acc[2 + (k >> 2)][k & 3] = fmaf((float)a1[k], ena, acc[2 + (k >> 2)][k & 3]);
#pragma unroll
            for (int k = 0; k < 8; ++k) acc[4 + (k >> 2)][k & 3] = fmaf((float)a2[k], ena, acc[4 + (k >> 2)][k & 3]);
#pragma unroll
            for (int k = 0; k < 8; ++k) acc[6 + (k >> 2)][k & 3] = fmaf((float)a3[k], ena, acc[6 + (k >> 2)][k & 3]);
#pragma unroll
            for (int k = 0; k < 8; ++k) acc[0 + (k >> 2)][k & 3] = fmaf((float)b0_[k], enb, acc[0 + (k >> 2)][k & 3]);
#pragma unroll
            for (int k = 0; k < 8; ++k) acc[2 + (k >> 2)][k & 3] = fmaf((float)b1_[k], enb, acc[2 + (k >> 2)][k & 3]);
#pragma unroll
            for (int k = 0; k < 8; ++k) acc[4 + (k >> 2)][k & 3] = fmaf((float)b2_[k], enb, acc[4 + (k >> 2)][k & 3]);
#pragma unroll
            for (int k = 0; k < 8; ++k) acc[6 + (k >> 2)][k & 3] = fmaf((float)b3_[k], enb, acc[6 + (k >> 2)][k & 3]);
        }
        if (ei < end) {
            int2 e = er[ei];
            float en = __int_as_float(e.y);
            const f16x8* rp = (const f16x8*)(hcol + (size_t)e.x * HID);
            f16x8 v0 = rp[0], v1 = rp[1], v2 = rp[2], v3 = rp[3];
#pragma unroll
            for (int k = 0; k < 8; ++k) acc[0 + (k >> 2)][k & 3] = fmaf((float)v0[k], en, acc[0 + (k >> 2)][k & 3]);
#pragma unroll
            for (int k = 0; k < 8; ++k) acc[2 + (k >> 2)][k & 3] = fmaf((float)v1[k], en, acc[2 + (k >> 2)][k & 3]);
#pragma unroll
            for (int k = 0; k < 8; ++k) acc[4 + (k >> 2)][k & 3] = fmaf((float)v2[k], en, acc[4 + (k >> 2)][k & 3]);
#pragma unroll
            for (int k = 0; k < 8; ++k) acc[6 + (k >> 2)][k & 3] = fmaf((float)v3[k], en, acc[6 + (k >> 2)][k & 3]);
        }
        _Float16* dst = &As[lane * 136 + w * 32];
#pragma unroll
        for (int v4 = 0; v4 < 4; ++v4) {
            f16x8 o;
#pragma unroll
            for (int k = 0; k < 8; ++k) o[k] = (_Float16)acc[v4 * 2 + (k >> 2)][k & 3];
            *(f16x8*)(dst + v4 * 8) = o;
        }
    }
    __syncthreads();

    // phase 2: MFMA 16x128x128; wave w owns m-tile rows w*16..w*16+15
    const int q = lane >> 4, c = lane & 15;
    f16x8 afr[4];
#pragma unroll
    for (int kk = 0; kk < 4; ++kk) afr[kk] = *(const f16x8*)(&As[(w * 16 + c) * 136 + kk * 32 + q * 8]);
    const f16x8* __restrict__ Bv = (const f16x8*)W1p;
    _Float16* Cst = &As[w * 2176];
#pragma unroll
    for (int j = 0; j < 8; ++j) {
        f32x4 cc = {0.f, 0.f, 0.f, 0.f};
#pragma unroll
        for (int kk = 0; kk < 4; ++kk)
            cc = __builtin_amdgcn_mfma_f32_16x16x32_f16(afr[kk], Bv[(j * 4 + kk) * 64 + lane], cc, 0, 0, 0);
        const float bi = b1[j * 16 + c];
#pragma unroll
        for (int r = 0; r < 4; ++r) Cst[(q * 4 + r) * 128 + j * 16 + c] = (_Float16)fmaxf(cc[r] + bi, 0.f);
    }
#pragma unroll
    for (int it = 0; it < 4; ++it) {
        int idx = it * 64 + lane;
        *(f16x8*)(h1 + (size_t)(blk * 64 + w * 16) * 128 + idx * 8) = *(const f16x8*)(&As[w * 2176 + idx * 8]);
    }
}

// ---------------- weight prep: WihT (f32) + MFMA fragment packs (f16) incl. Whh for GRU ----------
__global__ __launch_bounds__(256) void k_prep(const float* __restrict__ Wih, const float* __restrict__ Whh,
                                              const float* __restrict__ W1, const float* __restrict__ Wm,
                                              float* __restrict__ WihT, _Float16* __restrict__ W1p,
                                              _Float16* __restrict__ Wmp, _Float16* __restrict__ Whhp) {
    int i = blockIdx.x * 256 + threadIdx.x;  // 0..49151
    {
        int o = i >> 7, k = i & 127;
        WihT[k * 384 + o] = Wih[i];
    }
    {
        // Whh frag pack over full range: i = ((f)*64 + lane)*8 + e, f = (w*3+g)*4+kk
        int e = i & 7;
        int lane = (i >> 3) & 63;
        int f = i >> 9;  // 0..95
        int kk = f & 3, g = (f >> 2) % 3, wv = f / 12;
        int q = lane >> 4, c = lane & 15;
        Whhp[i] = (_Float16)Whh[(size_t)(g * 128 + 16 * wv + c) * 128 + kk * 32 + q * 8 + e];
    }
    if (i < 16384) {
        int f = i >> 9;          // frag id 0..31
        int j = f >> 2, kk = f & 3;
        int lane = (i >> 3) & 63;
        int e = i & 7;
        int q = lane >> 4, p = lane & 15;
        int k = kk * 32 + q * 8 + e, n = j * 16 + p;
        W1p[i] = (_Float16)W1[k * 128 + n];
        Wmp[i] = (_Float16)Wm[k * 128 + n];
    }
}

// ---------------- fused: GEMM2 (f16 MFMA) + relu + frame mean + gi precompute (time-major out) ----
__global__ __launch_bounds__(256) void k_mm_pool(const _Float16* __restrict__ h1, const _Float16* __restrict__ Wmp,
                                                 const float* __restrict__ bm, const float* __restrict__ WihT,
                                                 const float* __restrict__ bih, float* __restrict__ GIt) {
    __shared__ __align__(16) _Float16 As[80 * 136];
    __shared__ float colpart[4 * 128];
    __shared__ float fr[128];
    const int tid = threadIdx.x;
    const int w = tid >> 6, lane = tid & 63;
    const int q = lane >> 4, c = lane & 15;
    const int bt = blockIdx.x;
    const int bb = bt / T_SZ, tt = bt % T_SZ;

    const f16x8* __restrict__ srcv = (const f16x8*)(h1 + (size_t)bt * NPF * HID);
    for (int idx = tid; idx < 80 * 17; idx += 256) {
        int row = idx / 17, ch = idx % 17;
        f16x8 v;
        if (row < NPF && ch < 16) {
            v = srcv[row * 16 + ch];
        } else {
#pragma unroll
            for (int k = 0; k < 8; ++k) v[k] = (_Float16)0.f;
        }
        *(f16x8*)(&As[row * 136 + ch * 8]) = v;
    }
    __syncthreads();

    const f16x8* __restrict__ Bv = (const f16x8*)Wmp;
    const int npass = (w == 0) ? 2 : 1;
    for (int pass = 0; pass < npass; ++pass) {
        const int mt = pass ? 4 : w;
        f16x8 afr[4];
#pragma unroll
        for (int kk = 0; kk < 4; ++kk) afr[kk] = *(const f16x8*)(&As[(mt * 16 + c) * 136 + kk * 32 + q * 8]);
#pragma unroll
        for (int j = 0; j < 8; ++j) {
            f32x4 cc = {0.f, 0.f, 0.f, 0.f};
#pragma unroll
            for (int kk = 0; kk < 4; ++kk)
                cc = __builtin_amdgcn_mfma_f32_16x16x32_f16(afr[kk], Bv[(j * 4 + kk) * 64 + lane], cc, 0, 0, 0);
            const float bi = bm[j * 16 + c];
            float s = 0.f;
#pragma unroll
            for (int r = 0; r < 4; ++r) {
                int m = mt * 16 + q * 4 + r;
                float v = fmaxf(cc[r] + bi, 0.f);
                s += (m < NPF) ? v : 0.f;
            }
            s += __shfl_xor(s, 16);
            s += __shfl_xor(s, 32);
            if (lane < 16) {
                float* dst = &colpart[w * 128 + j * 16 + c];
                *dst = (pass == 0) ? s : (*dst + s);
            }
        }
    }
    __syncthreads();
    if (tid < 128)
        fr[tid] = (colpart[tid] + colpart[128 + tid] + colpart[256 + tid] + colpart[384 + tid]) * (1.0f / NPF);
    __syncthreads();
    if (tid < 128) {
#pragma unroll
        for (int p = 0; p < 3; ++p) {
            int o = tid + p * 128;
            float a = bih[o];
#pragma unroll 8
            for (int k = 0; k < 128; ++k) a = fmaf(fr[k], WihT[k * 384 + o], a);
            GIt[((size_t)tt * B_SZ + bb) * 384 + o] = a;  // time-major for the GRU
        }
    }
}

// ---------------- GRU recurrence: MFMA-batched (16 batches = M-tile), 2 blocks x 8 waves ----------
// Wave w owns n-tiles {w, 8+w, 16+w} = gates r/z/n of outputs 16w..16w+15 -> gate math is lane-local.
// Depth-2 GIt prefetch: loads for t+2 issued at step t (GIt is HBM-resident, ~900cyc; same-iteration
// prefetch left a per-step vmcnt stall in r7/r8). Gates use raw v_rcp/v_exp (no Newton-divide).
__global__ __launch_bounds__(512) __attribute__((amdgpu_waves_per_eu(1, 2)))
void k_gru(const float* __restrict__ GIt, const _Float16* __restrict__ Whhp,
           const float* __restrict__ bhh, float* __restrict__ hT) {
    __shared__ __align__(16) _Float16 hbuf[2][16 * 144];  // double buffer: one barrier/step
    const int tid = threadIdx.x;
    const int w = tid >> 6, lane = tid & 63;
    const int q = lane >> 4, c = lane & 15;
    const int B = blockIdx.x;  // batches 16B..16B+15
    const float LOG2E = 1.44269504f;

    // B-frags: pre-packed f16, 12 coalesced 16B loads (48 VGPRs)
    f16x8 bfr[3][4];
#pragma unroll
    for (int g = 0; g < 3; ++g)
#pragma unroll
        for (int kk = 0; kk < 4; ++kk)
            bfr[g][kk] = *(const f16x8*)(Whhp + (size_t)(((w * 3 + g) * 4 + kk) * 64 + lane) * 8);
    const float bh0 = bhh[16 * w + c], bh1 = bhh[128 + 16 * w + c], bh2 = bhh[256 + 16 * w + c];
    for (int i = tid; i < 16 * 144 / 2; i += 512) ((unsigned int*)hbuf[0])[i] = 0u;
    float h[4] = {0.f, 0.f, 0.f, 0.f};

    // GIt base offsets per row r (lane-invariant stride per step = B_SZ*384 floats)
    size_t gbase[4];
#pragma unroll
    for (int r = 0; r < 4; ++r) gbase[r] = (size_t)(B * 16 + q * 4 + r) * 384 + 16 * w + c;

    float gc[3][4], gn[3][4];
#pragma unroll
    for (int r = 0; r < 4; ++r)
#pragma unroll
        for (int g = 0; g < 3; ++g) {
            gc[g][r] = GIt[gbase[r] + g * 128];                           // t = 0
            gn[g][r] = GIt[(size_t)1 * B_SZ * 384 + gbase[r] + g * 128];  // t = 1
        }
    __syncthreads();

    for (int t = 0; t < T_SZ; ++t) {
        const _Float16* rb = hbuf[t & 1];
        _Float16* wb = hbuf[(t & 1) ^ 1];
        f16x8 afr[4];
#pragma unroll
        for (int kk = 0; kk < 4; ++kk) afr[kk] = *(const f16x8*)(&rb[c * 144 + kk * 32 + q * 8]);
        // prefetch step t+2 (consumed at end of t+1: hiding window >= one full step)
        float gn2[3][4];
        const size_t off2 = (size_t)((t + 2 < T_SZ) ? t + 2 : T_SZ - 1) * (B_SZ * 384);
#pragma unroll
        for (int r = 0; r < 4; ++r)
#pragma unroll
            for (int g = 0; g < 3; ++g) gn2[g][r] = GIt[off2 + gbase[r] + g * 128];
        f32x4 cc[3];
#pragma unroll
        for (int g = 0; g < 3; ++g) {
            f32x4 a = {0.f, 0.f, 0.f, 0.f};
#pragma unroll
            for (int kk = 0; kk < 4; ++kk) a = __builtin_amdgcn_mfma_f32_16x16x32_f16(afr[kk], bfr[g][kk], a, 0, 0, 0);
            cc[g] = a;
        }
#pragma unroll
        for (int r = 0; r < 4; ++r) {
            float hr = cc[0][r] + bh0, hz = cc[1][r] + bh1, hn = cc[2][r] + bh2;
            float rg = __builtin_amdgcn_rcpf(1.f + exp2f(-LOG2E * (gc[0][r] + hr)));
            float zg = __builtin_amdgcn_rcpf(1.f + exp2f(-LOG2E * (gc[1][r] + hz)));
            float arg = gc[2][r] + rg * hn;
            float nn = 1.f - 2.f * __builtin_amdgcn_rcpf(exp2f(2.f * LOG2E * arg) + 1.f);
            h[r] = (1.f - zg) * nn + zg * h[r];
            wb[(q * 4 + r) * 144 + 16 * w + c] = (_Float16)h[r];
        }
#pragma unroll
        for (int r = 0; r < 4; ++r)
#pragma unroll
            for (int g = 0; g < 3; ++g) {
                gc[g][r] = gn[g][r];
                gn[g][r] = gn2[g][r];
            }
        __syncthreads();  // new h visible for next step's frag reads
    }
#pragma unroll
    for (int r = 0; r < 4; ++r) hT[(size_t)(B * 16 + q * 4 + r) * 128 + 16 * w + c] = h[r];
}

// ---------------- classifier head (384 threads: phase 2 needs 320) ----------------
__global__ __launch_bounds__(384) void k_cls(const float* __restrict__ hT, const float* __restrict__ Wc1,
                                             const float* __restrict__ bc1, const float* __restrict__ Wc2,
                                             const float* __restrict__ bc2, float* __restrict__ out) {
    __shared__ float hid[32 * 64];
    int tid = threadIdx.x;
    for (int idx = tid; idx < 2048; idx += 384) {
        int b = idx >> 6, j = idx & 63;
        float a = bc1[j];
#pragma unroll 8
        for (int k = 0; k < 128; ++k) a = fmaf(hT[b * 128 + k], Wc1[k * 64 + j], a);
        hid[idx] = fmaxf(a, 0.f);
    }
    __syncthreads();
    if (tid < 320) {
        int b = tid / 10, c = tid % 10;
        float a = bc2[c];
#pragma unroll 8
        for (int k = 0; k < 64; ++k) a = fmaf(hid[b * 64 + k], Wc2[k * 10 + c], a);
        out[tid] = a;
    }
}

extern "C" void kernel_launch(void* const* d_in, const int* in_sizes, int n_in, void* d_out, int out_size, void* d_ws,
                              size_t ws_size, hipStream_t stream) {
    const float* x = (const float*)d_in[0];
    const int* ei = (const int*)d_in[1];
    const int* e_src = ei;
    const int* e_dst = ei + E_TOT;
    const float* W0 = (const float*)d_in[2];
    const float* b0 = (const float*)d_in[3];
    const float* W1 = (const float*)d_in[4];
    const float* b1 = (const float*)d_in[5];
    const float* Wm = (const float*)d_in[6];
    const float* bm = (const float*)d_in[7];
    const float* Wih = (const float*)d_in[8];
    const float* Whh = (const float*)d_in[9];
    const float* bih = (const float*)d_in[10];
    const float* bhh = (const float*)d_in[11];
    const float* Wc1 = (const float*)d_in[12];
    const float* bc1 = (const float*)d_in[13];
    const float* Wc2 = (const float*)d_in[14];
    const float* bc2 = (const float*)d_in[15];
    float* out = (float*)d_out;

    char* base = (char*)d_ws;
    size_t off = 0;
    auto alloc = [&](size_t bytes) {
        size_t o = off;
        off = (off + bytes + 255) & ~(size_t)255;
        return o;
    };
    size_t o_cnt = alloc((size_t)NN_TOT * 4);
    size_t o_cursor = alloc((size_t)NN_TOT * 4);  // contiguous with cnt for one memset
    size_t o_rowoff = alloc((size_t)(NN_TOT + 1) * 4);
    size_t o_bsums = alloc(256 * 4);
    size_t o_disqrt = alloc((size_t)NN_TOT * 4);
    size_t o_snorm = alloc((size_t)NN_TOT * 4);
    size_t o_er = alloc((size_t)E_TOT * 8);
    size_t o_gi = alloc((size_t)B_SZ * T_SZ * 384 * 4);
    size_t o_wiht = alloc((size_t)128 * 384 * 4);
    size_t o_w1p = alloc((size_t)128 * 128 * 2);
    size_t o_wmp = alloc((size_t)128 * 128 * 2);
    size_t o_whhp = alloc((size_t)128 * 384 * 2);
    size_t o_ht = alloc((size_t)B_SZ * 128 * 4);
    size_t o_h0 = alloc((size_t)NN_TOT * HID * 2);
    size_t o_h1 = alloc((size_t)NN_TOT * HID * 2);
    if (off > ws_size) return;  // workspace too small -> visible validation failure

    int* cnt = (int*)(base + o_cnt);
    int* cursor = (int*)(base + o_cursor);
    int* row_off = (int*)(base + o_rowoff);
    int* bsums = (int*)(base + o_bsums);
    float* d_isqrt = (float*)(base + o_disqrt);
    float* self_norm = (float*)(base + o_snorm);
    int2* er = (int2*)(base + o_er);
    float* GIt = (float*)(base + o_gi);
    float* WihT = (float*)(base + o_wiht);
    _Float16* W1p = (_Float16*)(base + o_w1p);
    _Float16* Wmp = (_Float16*)(base + o_wmp);
    _Float16* Whhp = (_Float16*)(base + o_whhp);
    float* hT = (float*)(base + o_ht);
    _Float16* h0 = (_Float16*)(base + o_h0);
    _Float16* h1 = (_Float16*)(base + o_h1);

    hipMemsetAsync(base + o_cnt, 0, (size_t)2 * NN_TOT * 4, stream);  // cnt + cursor

    k_deg<<<E_TOT / 1024, 256, 0, stream>>>((const int4*)e_dst, cnt);
    k_scan1<<<NN_TOT / 1024, 256, 0, stream>>>(cnt, row_off, bsums, d_isqrt, self_norm);
    k_scan2<<<1, 256, 0, stream>>>(bsums, NN_TOT / 1024);
    k_scan3<<<NN_TOT / 256, 256, 0, stream>>>(row_off, bsums);
    k_scatter<<<E_TOT / 256, 256, 0, stream>>>(e_src, e_dst, d_isqrt, row_off, cursor, er);
    k_prep<<<(384 * 128) / 256, 256, 0, stream>>>(Wih, Whh, W1, Wm, WihT, W1p, Wmp, Whhp);
    k_gcn0<<<NN_TOT / 64, 256, 0, stream>>>(x, row_off, er, self_norm, W0, b0, h0);
    k_agg_mm<<<NN_TOT / 64, 256, 0, stream>>>(h0, row_off, er, self_norm, W1p, b1, h1);
    k_mm_pool<<<B_SZ * T_SZ, 256, 0, stream>>>(h1, Wmp, bm, WihT, bih, GIt);
    k_gru<<<2, 512, 0, stream>>>(GIt, Whhp, bhh, hT);
    k_cls<<<1, 384, 0, stream>>>(hT, Wc1, bc1, Wc2, bc2, out);
}